// Round 1
// baseline (2665.105 us; speedup 1.0000x reference)
//
#include <hip/hip_runtime.h>

#define SEQ 128
#define BATCH 32
#define NTOKEN 32000
#define NINP 1024
#define NHID 1024
#define MTOT (SEQ * BATCH)  // 4096

typedef unsigned short u16;
typedef __attribute__((ext_vector_type(8))) short bf16x8;
typedef __attribute__((ext_vector_type(4))) float f32x4;

__device__ __forceinline__ u16 f2bf(float f) {
  unsigned u = __float_as_uint(f);
  u += 0x7FFFu + ((u >> 16) & 1u);  // round-to-nearest-even
  return (u16)(u >> 16);
}

// ---------------- cast fp32 -> bf16 (n multiple of 4) ----------------
__global__ void cast_f32_bf16(const float* __restrict__ s, u16* __restrict__ d, int n) {
  int i = (blockIdx.x * blockDim.x + threadIdx.x) * 4;
  int stride = gridDim.x * blockDim.x * 4;
  for (; i < n; i += stride) {
    float4 v = *(const float4*)(s + i);
    ushort4 o;
    o.x = f2bf(v.x); o.y = f2bf(v.y); o.z = f2bf(v.z); o.w = f2bf(v.w);
    *(ushort4*)(d + i) = o;
  }
}

// ---------------- embedding gather + cast: one block per (s,b) ----------------
__global__ __launch_bounds__(256) void embed_gather(const int* __restrict__ tok,
                                                    const float* __restrict__ embW,
                                                    u16* __restrict__ dst) {
  int m = blockIdx.x;  // 0..4095, = s*32+b
  int tk = tok[m];
  const float* src = embW + (size_t)tk * NINP;
  u16* d = dst + (size_t)m * NINP;
  int t = threadIdx.x;  // 256 threads * 4 elems = 1024
  float4 v = *(const float4*)(src + t * 4);
  ushort4 o;
  o.x = f2bf(v.x); o.y = f2bf(v.y); o.z = f2bf(v.z); o.w = f2bf(v.w);
  *(ushort4*)(d + t * 4) = o;
}

// ---------------- bf16 GEMM: C[M,N] = A[M,K] @ B[N,K]^T + bias, C fp32 ----------------
#define BM 128
#define BN 128
#define BK 32

__device__ __forceinline__ void gld_lds16(const u16* g, u16* l) {
  __builtin_amdgcn_global_load_lds((__attribute__((address_space(1))) unsigned int*)g,
                                   (__attribute__((address_space(3))) unsigned int*)l, 16, 0, 0);
}

__global__ __launch_bounds__(256) void gemm_bt_bias(const u16* __restrict__ A,
                                                    const u16* __restrict__ B,
                                                    const float* __restrict__ bias,
                                                    float* __restrict__ C,
                                                    int K, int ldc, int ntn) {
  __shared__ __align__(16) u16 As[BM * BK];
  __shared__ __align__(16) u16 Bs[BN * BK];
  int mt = blockIdx.x / ntn, nt = blockIdx.x % ntn;
  size_t m0 = (size_t)mt * BM, n0 = (size_t)nt * BN;
  int t = threadIdx.x, lane = t & 63;
  int w = t >> 6;
  int wr = w >> 1, wc = w & 1;  // 2x2 wave grid, wave tile 64x64
  // staging: thread t, chunk c covers LDS bytes [c*4096 + t*16, +16)
  int srow = t >> 2;           // 0..63
  int scol = (t & 3) * 8;      // bf16 elems
  const u16* Ag0 = A + (m0 + srow) * (size_t)K + scol;
  const u16* Ag1 = Ag0 + (size_t)64 * K;
  const u16* Bg0 = B + (n0 + srow) * (size_t)K + scol;
  const u16* Bg1 = Bg0 + (size_t)64 * K;
  u16* Al = As + t * 8;
  u16* Bl = Bs + t * 8;
  int rA = lane & 15;
  int koff = (lane >> 4) * 8;
  f32x4 acc[4][4] = {};
  for (int k0 = 0; k0 < K; k0 += BK) {
    gld_lds16(Ag0 + k0, Al);
    gld_lds16(Ag1 + k0, Al + 2048);
    gld_lds16(Bg0 + k0, Bl);
    gld_lds16(Bg1 + k0, Bl + 2048);
    __syncthreads();  // drains vmcnt: staged data visible
    bf16x8 af[4], bfr[4];
#pragma unroll
    for (int m = 0; m < 4; ++m)
      af[m] = *(const bf16x8*)(As + (wr * 64 + m * 16 + rA) * BK + koff);
#pragma unroll
    for (int n = 0; n < 4; ++n)
      bfr[n] = *(const bf16x8*)(Bs + (wc * 64 + n * 16 + rA) * BK + koff);
#pragma unroll
    for (int m = 0; m < 4; ++m)
#pragma unroll
      for (int n = 0; n < 4; ++n)
        acc[m][n] = __builtin_amdgcn_mfma_f32_16x16x32_bf16(af[m], bfr[n], acc[m][n], 0, 0, 0);
    __syncthreads();  // all reads done before next stage overwrites
  }
  int cr = lane >> 4;   // acc row group
  int cc = lane & 15;   // acc col
#pragma unroll
  for (int n = 0; n < 4; ++n) {
    size_t col = n0 + wc * 64 + n * 16 + cc;
    float bv = bias[col];
#pragma unroll
    for (int m = 0; m < 4; ++m) {
#pragma unroll
      for (int r = 0; r < 4; ++r) {
        size_t row = m0 + wr * 64 + m * 16 + cr * 4 + r;
        C[row * (size_t)ldc + col] = acc[m][n][r] + bv;
      }
    }
  }
}

// ---------------- one recurrence step: h_new = alpha[s]*tanh(xin + h@Whh^T + b_hh) ----------------
__global__ __launch_bounds__(128) void rnn_step(const u16* __restrict__ hprev,
                                                const u16* __restrict__ Whh,
                                                const float* __restrict__ xin_s,
                                                const float* __restrict__ b_hh,
                                                const float* __restrict__ alpha, int s,
                                                u16* __restrict__ hnext,
                                                u16* __restrict__ hs_out,
                                                float* __restrict__ hid_out) {
  int ng = blockIdx.x;  // 32 groups of 32 output cols
  int t = threadIdx.x, w = t >> 6, lane = t & 63;
  int rA = lane & 15, koff = (lane >> 4) * 8;
  const u16* Ab = hprev + (size_t)(w * 16 + rA) * NHID + koff;
  const u16* Bb0 = Whh + (size_t)(ng * 32 + rA) * NHID + koff;
  const u16* Bb1 = Bb0 + (size_t)16 * NHID;
  f32x4 acc0 = {}, acc1 = {};
#pragma unroll 4
  for (int k0 = 0; k0 < NHID; k0 += 32) {
    bf16x8 a = *(const bf16x8*)(Ab + k0);
    bf16x8 b0 = *(const bf16x8*)(Bb0 + k0);
    bf16x8 b1 = *(const bf16x8*)(Bb1 + k0);
    acc0 = __builtin_amdgcn_mfma_f32_16x16x32_bf16(a, b0, acc0, 0, 0, 0);
    acc1 = __builtin_amdgcn_mfma_f32_16x16x32_bf16(a, b1, acc1, 0, 0, 0);
  }
  float al = alpha[s];
  int cr = lane >> 4, cc = lane & 15;
#pragma unroll
  for (int n = 0; n < 2; ++n) {
    f32x4 acc = n ? acc1 : acc0;
    int j = ng * 32 + n * 16 + cc;
    float bb = b_hh[j];
#pragma unroll
    for (int r = 0; r < 4; ++r) {
      int b = w * 16 + cr * 4 + r;
      float v = al * tanhf(xin_s[b * NHID + j] + acc[r] + bb);
      u16 bv = f2bf(v);
      hnext[b * NHID + j] = bv;
      hs_out[b * NHID + j] = bv;
      if (s == SEQ - 1) hid_out[b * NHID + j] = v;
    }
  }
}

extern "C" void kernel_launch(void* const* d_in, const int* in_sizes, int n_in,
                              void* d_out, int out_size, void* d_ws, size_t ws_size,
                              hipStream_t stream) {
  const int* tok = (const int*)d_in[0];
  const float* hidden = (const float*)d_in[1];
  const float* embW = (const float*)d_in[2];
  const float* W_ih = (const float*)d_in[3];
  const float* W_hh = (const float*)d_in[4];
  const float* b_ih = (const float*)d_in[5];
  const float* b_hh = (const float*)d_in[6];
  const float* alpha = (const float*)d_in[7];
  const float* dec_W = (const float*)d_in[8];
  const float* dec_b = (const float*)d_in[9];
  float* out_dec = (float*)d_out;                          // [4096][32000]
  float* out_hid = out_dec + (size_t)MTOT * NTOKEN;        // [32][1024]

  char* ws = (char*)d_ws;
  u16* dec_Wb = (u16*)(ws);                 // 65,536,000 B
  u16* hs_b = (u16*)(ws + 65536000);        //  8,388,608 B
  float* xin = (float*)(ws + 73924608);     // 16,777,216 B
  u16* embb = (u16*)(ws + 90701824);        //  8,388,608 B
  u16* W_ihb = (u16*)(ws + 99090432);       //  2,097,152 B
  u16* W_hhb = (u16*)(ws + 101187584);      //  2,097,152 B
  u16* hbuf0 = (u16*)(ws + 103284736);      //     65,536 B
  u16* hbuf1 = (u16*)(ws + 103350272);      //     65,536 B

  hipLaunchKernelGGL(cast_f32_bf16, dim3(2048), dim3(256), 0, stream, dec_W, dec_Wb, NTOKEN * NINP);
  hipLaunchKernelGGL(cast_f32_bf16, dim3(1024), dim3(256), 0, stream, W_ih, W_ihb, NHID * NINP);
  hipLaunchKernelGGL(cast_f32_bf16, dim3(1024), dim3(256), 0, stream, W_hh, W_hhb, NHID * NHID);
  hipLaunchKernelGGL(cast_f32_bf16, dim3(32), dim3(256), 0, stream, hidden, hbuf0, BATCH * NHID);
  hipLaunchKernelGGL(embed_gather, dim3(MTOT), dim3(256), 0, stream, tok, embW, embb);

  // xin = embb @ W_ih^T + b_ih  (M=4096, N=1024, K=1024), fp32 out
  hipLaunchKernelGGL(gemm_bt_bias, dim3((MTOT / BM) * (NHID / BN)), dim3(256), 0, stream,
                     embb, W_ihb, b_ih, xin, NINP, NHID, NHID / BN);

  for (int s = 0; s < SEQ; ++s) {
    const u16* hp = (s & 1) ? hbuf1 : hbuf0;
    u16* hn = (s & 1) ? hbuf0 : hbuf1;
    hipLaunchKernelGGL(rnn_step, dim3(NHID / 32), dim3(128), 0, stream,
                       hp, W_hhb, xin + (size_t)s * BATCH * NHID, b_hh, alpha, s,
                       hn, hs_b + (size_t)s * BATCH * NHID, out_hid);
  }

  // decoded = hs @ dec_W^T + dec_b  (M=4096, N=32000, K=1024), fp32 out
  hipLaunchKernelGGL(gemm_bt_bias, dim3((MTOT / BM) * (NTOKEN / BN)), dim3(256), 0, stream,
                     hs_b, dec_Wb, dec_b, out_dec, NHID, NTOKEN, NTOKEN / BN);
}